// Round 6
// baseline (240.567 us; speedup 1.0000x reference)
//
#include <hip/hip_runtime.h>

#define B_ 4
#define T_ 2048
#define D_ 512
#define H_ 8
#define DK_ 64
#define TBL 4095

typedef __attribute__((ext_vector_type(4))) float f32x4;
typedef __attribute__((ext_vector_type(8))) short bf16x8;
typedef __attribute__((ext_vector_type(4))) int i32x4;

static __device__ __forceinline__ float b2f(ushort u) {
    union { float f; unsigned int i; } c;
    c.i = ((unsigned int)u) << 16;
    return c.f;
}

static __device__ __forceinline__ ushort f2b(float f) {
    union { float f; unsigned int i; } c;
    c.f = f;
    unsigned int i = c.i;
    unsigned int r = (i + 0x7fffu + ((i >> 16) & 1u)) >> 16;
    return (ushort)r;
}

// ---------------------------------------------------------------------------
// mask width detection: flags[0] = 0 (4-byte int/f32), 1 (1-byte), 2 (2-byte)
__global__ __launch_bounds__(64) void detect_mask_kernel(const unsigned int* __restrict__ mask,
                                                         int* __restrict__ flags) {
    int lane = threadIdx.x;
    int c2 = 0, c1 = 0;
    for (int i = lane; i < 512; i += 64) {
        unsigned int v = mask[i];
        c2 += (v == 0x3F803F80u || v == 0x00010001u) ? 1 : 0;
        c1 += (v == 0x01010101u) ? 1 : 0;
    }
#pragma unroll
    for (int m = 1; m < 64; m <<= 1) {
        c2 += __shfl_xor(c2, m);
        c1 += __shfl_xor(c1, m);
    }
    if (lane == 0) flags[0] = (c2 > 8) ? 2 : ((c1 > 8) ? 1 : 0);
}

__global__ __launch_bounds__(256) void mask_prep_kernel(const void* __restrict__ mask,
                                                        const int* __restrict__ flags,
                                                        int* __restrict__ maskw) {
    int j = blockIdx.x * 256 + threadIdx.x;   // 0..8191
    int fm = flags[0];
    int v;
    if (fm == 2)      v = (((const ushort*)mask)[j] != 0);
    else if (fm == 1) v = (((const unsigned char*)mask)[j] != 0);
    else              v = (((const int*)mask)[j] != 0);
    maskw[j] = v;
}

// ---------------------------------------------------------------------------
// weights f32 -> bf16 (4 weights, z selects)
__global__ __launch_bounds__(256) void wcvt_kernel(
    const float* __restrict__ W0, const float* __restrict__ W1,
    const float* __restrict__ W2, const float* __restrict__ W3,
    ushort* __restrict__ Wc) {
    const int z = blockIdx.z;
    const float* Ws = (z == 0) ? W0 : ((z == 1) ? W1 : ((z == 2) ? W2 : W3));
    int idx = blockIdx.x * 256 + threadIdx.x;    // 0..32767, 8 elements each
    const float* wf = Ws + idx * 8;
    f32x4 a = *(const f32x4*)(wf);
    f32x4 c = *(const f32x4*)(wf + 4);
    union { ushort u[8]; i32x4 v; } o;
#pragma unroll
    for (int j = 0; j < 4; ++j) { o.u[j] = f2b(a[j]); o.u[4 + j] = f2b(c[j]); }
    *(i32x4*)(Wc + (size_t)z * (D_ * D_) + idx * 8) = o.v;
}

// ---------------------------------------------------------------------------
// xp = bf16(x + sinusoidal_pe(t, d)); one thread per (row, dim-pair).
__global__ __launch_bounds__(256) void pe_kernel(const float* __restrict__ x,
                                                 ushort* __restrict__ xp) {
    int idx = blockIdx.x * 256 + threadIdx.x;
    int i = idx & 255;        // pair index (dims 2i, 2i+1)
    int row = idx >> 8;       // b*T + t
    int t = row & (T_ - 1);
    float div = __expf((float)i * -0.035977892f);   // exp(-(2i)*ln(1e4)/512)
    float ang = (float)t * div;
    float s = sinf(ang);
    float c = cosf(ang);
    float2 v = ((const float2*)x)[row * 256 + i];
    unsigned int o = (unsigned int)f2b(v.x + s) | ((unsigned int)f2b(v.y + c) << 16);
    *(unsigned int*)(xp + (size_t)row * D_ + 2 * i) = o;
}

// ---------------------------------------------------------------------------
// antisymmetric rel-pos bias table tbl[h][j] = 0.5*(E[j,h]-E[4094-j,h])
__global__ __launch_bounds__(256) void bias_tbl_kernel(const float* __restrict__ E,
                                                       float* __restrict__ tbl) {
    int idx = blockIdx.x * 256 + threadIdx.x;
    if (idx >= TBL * H_) return;
    int h = idx & 7;
    int j = idx >> 3;
    tbl[(size_t)h * TBL + j] = 0.5f * (E[(size_t)j * H_ + h] - E[(size_t)(4094 - j) * H_ + h]);
}

// ---------------------------------------------------------------------------
// GEMM: C[m][n] = sum_k A[m][k] * W[n][k] + bias[n]  (bf16 in, f32 acc)
// M=8192, N=512, K=512. 128x128 tile, 4 waves.
// OUTMODE 0: bf16 out, [b][h][t][dk] head-split (Q/K/V).
// OUTMODE 1: f32 out, row-major [m][n] (final output).
template <int OUTMODE>
__global__ __launch_bounds__(256) void gemm_bt_kernel(
    const ushort* __restrict__ A,
    const ushort* __restrict__ W0, const ushort* __restrict__ W1, const ushort* __restrict__ W2,
    const float* __restrict__ bias0, const float* __restrict__ bias1, const float* __restrict__ bias2,
    void* __restrict__ O0, void* __restrict__ O1, void* __restrict__ O2) {
    __shared__ ushort As[128 * 32];
    __shared__ ushort Bs[128 * 32];

    const int z = blockIdx.z;
    const ushort* Wp = (z == 0) ? W0 : ((z == 1) ? W1 : W2);
    const float* bp = (z == 0) ? bias0 : ((z == 1) ? bias1 : bias2);
    void* Op = (z == 0) ? O0 : ((z == 1) ? O1 : O2);

    const int n0 = blockIdx.x * 128;
    const int m0 = blockIdx.y * 128;
    const int tid = threadIdx.x;
    const int lane = tid & 63;
    const int w = tid >> 6;
    const int wr = (w >> 1) * 64;
    const int wc = (w & 1) * 64;
    const int l15 = lane & 15;
    const int lg = lane >> 4;

    f32x4 acc[4][4];
#pragma unroll
    for (int mi = 0; mi < 4; ++mi)
#pragma unroll
        for (int ni = 0; ni < 4; ++ni)
            acc[mi][ni] = (f32x4){0.f, 0.f, 0.f, 0.f};

    for (int kt = 0; kt < D_ / 32; ++kt) {
#pragma unroll
        for (int p = 0; p < 2; ++p) {
            int c = tid + p * 256;      // 0..511 chunks of 16B
            int r = c >> 2;
            int s = c & 3;
            i32x4 va = *(const i32x4*)(A + (size_t)(m0 + r) * D_ + kt * 32 + s * 8);
            i32x4 vb = *(const i32x4*)(Wp + (size_t)(n0 + r) * D_ + kt * 32 + s * 8);
            *(i32x4*)(As + r * 32 + s * 8) = va;
            *(i32x4*)(Bs + r * 32 + s * 8) = vb;
        }
        __syncthreads();

        bf16x8 af[4], bfr[4];
#pragma unroll
        for (int mi = 0; mi < 4; ++mi)
            af[mi] = *(const bf16x8*)(As + (wr + mi * 16 + l15) * 32 + lg * 8);
#pragma unroll
        for (int ni = 0; ni < 4; ++ni)
            bfr[ni] = *(const bf16x8*)(Bs + (wc + ni * 16 + l15) * 32 + lg * 8);
#pragma unroll
        for (int mi = 0; mi < 4; ++mi)
#pragma unroll
            for (int ni = 0; ni < 4; ++ni)
                acc[mi][ni] = __builtin_amdgcn_mfma_f32_16x16x32_bf16(af[mi], bfr[ni], acc[mi][ni], 0, 0, 0);
        __syncthreads();
    }

#pragma unroll
    for (int ni = 0; ni < 4; ++ni) {
        int n = n0 + wc + ni * 16 + l15;
        float bv = bp[n];
#pragma unroll
        for (int mi = 0; mi < 4; ++mi) {
#pragma unroll
            for (int i = 0; i < 4; ++i) {
                int m = m0 + wr + mi * 16 + lg * 4 + i;
                float v = acc[mi][ni][i] + bv;
                if (OUTMODE == 0) {
                    int b = m >> 11;
                    int t = m & 2047;
                    int h = n >> 6;
                    int dk = n & 63;
                    ((ushort*)Op)[(((size_t)(b * H_ + h) * T_ + t) << 6) + dk] = f2b(v);
                } else {
                    ((float*)Op)[(size_t)m * D_ + n] = v;   // f32 final output
                }
            }
        }
    }
}

// ---------------------------------------------------------------------------
// fused attention: Q/K/V in [b][h][t][dk]. Scores bounded -> plain exp safe;
// masked keys get weight 0 (== -inf score semantics; missing_bias is no-op).
__global__ __launch_bounds__(256) void attn_kernel(
    const ushort* __restrict__ Q, const ushort* __restrict__ K, const ushort* __restrict__ V,
    const int* __restrict__ maskw, const float* __restrict__ tbl,
    ushort* __restrict__ Aout) {
    __shared__ ushort Ks[64 * 64];
    __shared__ ushort Vs[64 * 64];
    __shared__ ushort Ps[4][32 * 64];
    __shared__ float biasl[2176];
    __shared__ float maskl[T_];

    const int qb = blockIdx.x;   // 0..15
    const int bh = blockIdx.y;   // 0..31
    const int b = bh >> 3;
    const int h = bh & 7;
    const int tid = threadIdx.x;
    const int lane = tid & 63;
    const int w = tid >> 6;
    const int l15 = lane & 15;
    const int lg = lane >> 4;

    const ushort* Qp = Q + (size_t)bh * T_ * DK_;
    const ushort* Kp = K + (size_t)bh * T_ * DK_;
    const ushort* Vp = V + (size_t)bh * T_ * DK_;

    for (int j = tid; j < 2176; j += 256) {
        int gj = qb * 128 + j;
        biasl[j] = (gj <= 4094) ? tbl[(size_t)h * TBL + gj] : 0.f;
    }
    for (int j = tid; j < T_; j += 256)
        maskl[j] = (maskw[b * T_ + j] != 0) ? 1.0f : 0.0f;

    const int q0 = qb * 128 + w * 32;
    bf16x8 qf[2][2];
#pragma unroll
    for (int mi = 0; mi < 2; ++mi)
#pragma unroll
        for (int kf = 0; kf < 2; ++kf)
            qf[mi][kf] = *(const bf16x8*)(Qp + (size_t)(q0 + mi * 16 + l15) * DK_ + kf * 32 + lg * 8);

    f32x4 acc[2][4];
    float rs[2][4];
#pragma unroll
    for (int mi = 0; mi < 2; ++mi) {
#pragma unroll
        for (int ni = 0; ni < 4; ++ni)
            acc[mi][ni] = (f32x4){0.f, 0.f, 0.f, 0.f};
#pragma unroll
        for (int i = 0; i < 4; ++i)
            rs[mi][i] = 0.f;
    }
    __syncthreads();

    for (int kt = 0; kt < T_ / 64; ++kt) {
        // stage K tile [64 keys][64 dk], slot-swizzled
#pragma unroll
        for (int p = 0; p < 2; ++p) {
            int c = tid + p * 256;
            int r = c >> 3;
            int s = c & 7;
            i32x4 v = *(const i32x4*)(Kp + (size_t)(kt * 64 + r) * DK_ + s * 8);
            *(i32x4*)(Ks + r * 64 + ((s ^ (r & 7)) * 8)) = v;
        }
        // stage V transposed: Vs[dk][key]; wave w owns dk rows [w*16, w*16+16)
        {
            int p2 = lane & 31;
            int half = lane >> 5;
            int dk0 = w * 16 + half * 8;
            const ushort* src = Vp + (size_t)(kt * 64 + 2 * p2) * DK_ + dk0;
            i32x4 lo = *(const i32x4*)(src);
            i32x4 hi = *(const i32x4*)(src + DK_);
            const ushort* plo = (const ushort*)&lo;
            const ushort* phi = (const ushort*)&hi;
#pragma unroll
            for (int j = 0; j < 8; ++j) {
                int dk = dk0 + j;
                unsigned int word = (unsigned int)plo[j] | ((unsigned int)phi[j] << 16);
                int slot = p2 >> 2;
                int wi = p2 & 3;
                *(unsigned int*)(Vs + dk * 64 + ((slot ^ (dk & 7)) * 8) + wi * 2) = word;
            }
        }
        __syncthreads();

        // S = Q K^T ; P = mask * exp(S/8 + bias); P -> per-wave LDS
#pragma unroll
        for (int ct = 0; ct < 4; ++ct) {
            int krow = ct * 16 + l15;
            bf16x8 kf0 = *(const bf16x8*)(Ks + krow * 64 + (((0 + lg) ^ (krow & 7)) * 8));
            bf16x8 kf1 = *(const bf16x8*)(Ks + krow * 64 + (((4 + lg) ^ (krow & 7)) * 8));
            int kg = kt * 64 + ct * 16 + l15;
            float mf = maskl[kg];
#pragma unroll
            for (int mi = 0; mi < 2; ++mi) {
                f32x4 S = (f32x4){0.f, 0.f, 0.f, 0.f};
                S = __builtin_amdgcn_mfma_f32_16x16x32_bf16(qf[mi][0], kf0, S, 0, 0, 0);
                S = __builtin_amdgcn_mfma_f32_16x16x32_bf16(qf[mi][1], kf1, S, 0, 0, 0);
                int ql0 = w * 32 + mi * 16 + lg * 4;
#pragma unroll
                for (int i = 0; i < 4; ++i) {
                    float bias = biasl[ql0 + i - kg + 2047];
                    float pv = mf * __expf(fmaf(S[i], 0.125f, bias));
                    ushort pb = f2b(pv);
                    rs[mi][i] += b2f(pb);
                    int prow = mi * 16 + lg * 4 + i;
                    int pcol = ct * 16 + l15;
                    Ps[w][prow * 64 + (((pcol >> 3) ^ (prow & 7)) * 8) + (pcol & 7)] = pb;
                }
            }
        }

        // PV accumulate
#pragma unroll
        for (int kk = 0; kk < 2; ++kk) {
            bf16x8 pf[2];
#pragma unroll
            for (int mi = 0; mi < 2; ++mi) {
                int prow = mi * 16 + l15;
                pf[mi] = *(const bf16x8*)(Ps[w] + prow * 64 + (((kk * 4 + lg) ^ (prow & 7)) * 8));
            }
#pragma unroll
            for (int ni = 0; ni < 4; ++ni) {
                int vrow = ni * 16 + l15;
                bf16x8 vf = *(const bf16x8*)(Vs + vrow * 64 + (((kk * 4 + lg) ^ (vrow & 7)) * 8));
#pragma unroll
                for (int mi = 0; mi < 2; ++mi)
                    acc[mi][ni] = __builtin_amdgcn_mfma_f32_16x16x32_bf16(pf[mi], vf, acc[mi][ni], 0, 0, 0);
            }
        }
        __syncthreads();
    }

#pragma unroll
    for (int mi = 0; mi < 2; ++mi)
#pragma unroll
        for (int i = 0; i < 4; ++i) {
            float v = rs[mi][i];
            v += __shfl_xor(v, 1);
            v += __shfl_xor(v, 2);
            v += __shfl_xor(v, 4);
            v += __shfl_xor(v, 8);
            rs[mi][i] = v;
        }

    // attention output in [b][t][h*64+d] (row-major for the final GEMM)
#pragma unroll
    for (int mi = 0; mi < 2; ++mi)
#pragma unroll
        for (int ni = 0; ni < 4; ++ni)
#pragma unroll
            for (int i = 0; i < 4; ++i) {
                int t = q0 + mi * 16 + lg * 4 + i;
                int d = h * DK_ + ni * 16 + l15;
                Aout[(size_t)(b * T_ + t) * D_ + d] = f2b(acc[mi][ni][i] / rs[mi][i]);
            }
}

// ---------------------------------------------------------------------------
extern "C" void kernel_launch(void* const* d_in, const int* in_sizes, int n_in,
                              void* d_out, int out_size, void* d_ws, size_t ws_size,
                              hipStream_t stream) {
    const float* x   = (const float*)d_in[0];
    const void* mask = d_in[1];
    const float* Wq  = (const float*)d_in[2];
    const float* bq  = (const float*)d_in[3];
    const float* Wk  = (const float*)d_in[4];
    const float* bk  = (const float*)d_in[5];
    const float* Wv  = (const float*)d_in[6];
    const float* bv  = (const float*)d_in[7];
    const float* Wo  = (const float*)d_in[8];
    const float* bo  = (const float*)d_in[9];
    const float* E   = (const float*)d_in[11];
    float* out = (float*)d_out;   // reference output dtype is FLOAT32

    char* ws = (char*)d_ws;
    ushort* xp  = (ushort*)(ws);                 // 8 MB (xp, later attn out)
    ushort* Qw  = (ushort*)(ws + (8u << 20));    // 8 MB  [b][h][t][dk]
    ushort* Kw  = (ushort*)(ws + (16u << 20));   // 8 MB
    ushort* Vw  = (ushort*)(ws + (24u << 20));   // 8 MB
    float* tbl  = (float*)(ws + (32u << 20));               // 131 KB (256 KB reserved)
    ushort* Wc  = (ushort*)(ws + (32u << 20) + 262144);     // 2 MB
    int* maskw  = (int*)(ws + (34u << 20) + 262144);        // 32 KB
    int* flags  = (int*)(ws + (34u << 20) + 262144 + 32768);

    if (ws_size < (35u << 20)) return;

    detect_mask_kernel<<<1, 64, 0, stream>>>((const unsigned int*)mask, flags);
    mask_prep_kernel<<<(B_ * T_) / 256, 256, 0, stream>>>(mask, flags, maskw);
    bias_tbl_kernel<<<(TBL * H_ + 255) / 256, 256, 0, stream>>>(E, tbl);
    pe_kernel<<<B_ * T_, 256, 0, stream>>>(x, xp);

    dim3 gw(128, 1, 4);
    wcvt_kernel<<<gw, 256, 0, stream>>>(Wq, Wk, Wv, Wo, Wc);

    dim3 g1(D_ / 128, (B_ * T_) / 128, 3);
    gemm_bt_kernel<0><<<g1, 256, 0, stream>>>(xp, Wc, Wc + D_ * D_, Wc + 2 * D_ * D_,
                                              bq, bk, bv, Qw, Kw, Vw);

    dim3 g2(T_ / 128, B_ * H_, 1);
    attn_kernel<<<g2, 256, 0, stream>>>(Qw, Kw, Vw, maskw, tbl, xp);

    dim3 g3(D_ / 128, (B_ * T_) / 128, 1);
    gemm_bt_kernel<1><<<g3, 256, 0, stream>>>(xp, Wc + 3 * D_ * D_, Wc + 3 * D_ * D_, Wc + 3 * D_ * D_,
                                              bo, bo, bo, out, out, out);
}